// Round 7
// baseline (17597.949 us; speedup 1.0000x reference)
//
#include <hip/hip_runtime.h>
#include <hip/hip_cooperative_groups.h>
#include <hip/hip_fp16.h>
#include <math.h>

namespace cg = cooperative_groups;

#define UNITS  256
#define BATCH  32768
#define R      16                 /* rows per chunk */
#define NCHUNK (BATCH / R)        /* 2048 */
#define TPB    512                /* 8 waves, each owns 2 n-tiles (NT=2) */

typedef float    f32x4 __attribute__((ext_vector_type(4)));
typedef _Float16 f16x8 __attribute__((ext_vector_type(8)));

__device__ __forceinline__ float uni(float x) {   // force wave-uniform -> SGPR
    return __uint_as_float(__builtin_amdgcn_readfirstlane(__float_as_uint(x)));
}

__device__ __forceinline__ float tanhd(float v) {
    float e = __expf(v + v);
    return 1.0f - 2.0f / (e + 1.0f);
}

// padded frag layout: unit (16B) -> u16 offset; 16B pad after every 8 units
__device__ __forceinline__ int puidx(int unit) {
    return (unit << 3) + ((unit >> 3) << 3);
}

__device__ __forceinline__ void blockAtomicMax2(unsigned* addr, float v, float* redbuf, int tid)
{
    #pragma unroll
    for (int o = 32; o > 0; o >>= 1) v = fmaxf(v, __shfl_xor(v, o, 64));
    if ((tid & 63) == 0) redbuf[tid >> 6] = v;
    __syncthreads();
    if (tid == 0) {
        float m = redbuf[0];
        #pragma unroll
        for (int i = 1; i < TPB / 64; ++i) m = fmaxf(m, redbuf[i]);
        atomicMax(addr, __float_as_uint(m));   // values >= 0: uint order == float order
    }
    __syncthreads();
}

// ---- init: symmetric zero-diag Ws -> fp16 hi + fp16 lo, B-fragment order ----
__global__ void init_ws_kernel(const float* __restrict__ W,
                               unsigned short* __restrict__ WfH,
                               unsigned short* __restrict__ WfL,
                               unsigned* __restrict__ scal)
{
    const int i = blockIdx.x * 256 + threadIdx.x;    // 0..65535
    const int k = i >> 8, n = i & 255;
    float v = 0.5f * (W[(k << 8) + n] + W[(n << 8) + k]);
    if (k == n) v = 0.0f;
    __half h = __float2half_rn(v);
    __half l = __float2half_rn(v - __half2float(h));
    // fragment order: [nt(16)][ks(8)][lane(64)][slot(8)]
    const int nt = n >> 4, ks = k >> 5;
    const int lane = (n & 15) + (((k >> 3) & 3) << 4);
    const int slot = k & 7;
    const int off = ((nt * 8 + ks) * 64 + lane) * 8 + slot;
    WfH[off] = __half_as_ushort(h);
    WfL[off] = __half_as_ushort(l);
    if (i < 8) scal[i] = 0u;
}

// ---- persistent cooperative solver --------------------------------------
__global__ void __launch_bounds__(TPB, 4) hopfield_solver(
    float* __restrict__ xA, float* __restrict__ xB,
    const float* __restrict__ bvec,
    const f16x8* __restrict__ WfH, const f16x8* __restrict__ WfL,
    unsigned* __restrict__ scal)
{
    cg::grid_group grid = cg::this_grid();
    __shared__ __align__(16) unsigned short XH[2][4608];   // fp16 A-frags, dbuf
    __shared__ float redbuf[TPB / 64];
    __shared__ float bc2[2];

    const int tid = threadIdx.x;
    const int l = tid & 63, w = tid >> 6;        // 8 waves

    // ownership: wave w -> n-tiles 2w, 2w+1; thread: cols n0, n1; rows mb..mb+3
    const int n0 = (w << 5) + (l & 15);
    const int n1 = n0 + 16;
    const int mb = (l >> 4) << 2;
    const float bn0 = bvec[n0], bn1 = bvec[n1];

    // A-frag write targets (same verified mapping as prior rounds)
    const int s_slot = l & 7;
    const int gk0 = (l & 15) >> 3;
    const int pb0 = puidx((n0 >> 5) * 64 + gk0 * 16 + mb) + s_slot;       // + 8*g
    const int pb1 = puidx((n0 >> 5) * 64 + (gk0 + 2) * 16 + mb) + s_slot; // + 8*g
    // A-frag read base: unit ks*64 + l  ->  u16 offset ks*576 + lbase
    const int lbase = (l << 3) + ((l >> 3) << 3);

    // resident W-hi fp16 B-fragments for this wave's two n-tiles (64 VGPR)
    f16x8 BH0[8], BH1[8];
    {
        const int nt0 = w * 2;
        #pragma unroll
        for (int ks = 0; ks < 8; ++ks) {
            BH0[ks] = WfH[(nt0 * 8 + ks) * 64 + l];
            BH1[ks] = WfH[((nt0 + 1) * 8 + ks) * 64 + l];
        }
    }

    auto writeFrag = [&](int p, const __half2 (&v2)[4]) {
        #pragma unroll
        for (int g = 0; g < 4; ++g) {
            XH[p][pb0 + 8 * g] = __half_as_ushort(__low2half(v2[g]));
            XH[p][pb1 + 8 * g] = __half_as_ushort(__high2half(v2[g]));
        }
    };

    auto matmul = [&](int p, f32x4& acc0, f32x4& acc1) {   // 1-term fp16
        #pragma unroll
        for (int ks = 0; ks < 8; ++ks) {
            const f16x8 aH = *(const f16x8*)&XH[p][ks * 576 + lbase];
            acc0 = __builtin_amdgcn_mfma_f32_16x16x32_f16(aH, BH0[ks], acc0, 0, 0, 0);
            acc1 = __builtin_amdgcn_mfma_f32_16x16x32_f16(aH, BH1[ks], acc1, 0, 0, 0);
        }
    };

    float* xc = xA;   // current x (d_out holds x0)
    float* xn = xB;
    float t = 0.0f, dt = 0.1f;
    const int nt0 = w * 2;

    for (int it = 0; it < 100000; ++it) {
        if (blockIdx.x == 0 && tid == 0) {
            scal[(it + 1) % 3] = 0u;          // err slot for next iter
            scal[3 + (it + 1) % 3] = 0u;      // pvf slot for next iter
        }

        // dt-premultiplied RKF coefficients, forced uniform (SGPR)
        const float a21 = uni(0.25f * dt);
        const float a31 = uni((float)(3.0 / 32.0) * dt),   a32 = uni((float)(9.0 / 32.0) * dt);
        const float a41 = uni((float)(1932.0 / 2197.0) * dt), a42 = uni((float)(-7200.0 / 2197.0) * dt),
                    a43 = uni((float)(7296.0 / 2197.0) * dt);
        const float a51 = uni((float)(439.0 / 216.0) * dt), a52 = uni(-8.0f * dt),
                    a53 = uni((float)(3680.0 / 513.0) * dt), a54 = uni((float)(-845.0 / 4104.0) * dt);
        const float a61 = uni((float)(-8.0 / 27.0) * dt),  a62 = uni(2.0f * dt),
                    a63 = uni((float)(-3544.0 / 2565.0) * dt), a64 = uni((float)(1859.0 / 4104.0) * dt),
                    a65 = uni((float)(-11.0 / 40.0) * dt);
        const float c41 = uni((float)(25.0 / 216.0) * dt), c43 = uni((float)(1408.0 / 2565.0) * dt),
                    c44 = uni((float)(2197.0 / 4104.0) * dt), c45 = uni(-0.2f * dt);
        const float c51 = uni((float)(16.0 / 135.0) * dt), c53 = uni((float)(6656.0 / 12825.0) * dt),
                    c54 = uni((float)(28561.0 / 56430.0) * dt), c55 = uni((float)(-9.0 / 50.0) * dt),
                    c56 = uni((float)(2.0 / 55.0) * dt);

        float em = 0.0f, pm = 0.0f;

        for (int ch = blockIdx.x; ch < NCHUNK; ch += gridDim.x) {
            const size_t rowbase = (size_t)(ch * R + mb) * UNITS;

            float xr0[4], xr1[4];
            __half2 x2[4], xt2[4], k1h[4], k2h[4], k3h[4], k4h[4], k5h[4];
            f32x4 acc0, acc1;

            #pragma unroll
            for (int g = 0; g < 4; ++g) {
                xr0[g] = xc[rowbase + (size_t)g * UNITS + n0];
                xr1[g] = xc[rowbase + (size_t)g * UNITS + n1];
                x2[g]  = __floats2half2_rn(xr0[g], xr1[g]);
            }

            // ---- stage 1: k1 = pvf(x); A = fp16(x), B = Wh + Wl (2-term) ----
            writeFrag(1, x2);
            __syncthreads();
            acc0 = {0.f, 0.f, 0.f, 0.f}; acc1 = {0.f, 0.f, 0.f, 0.f};
            #pragma unroll
            for (int ks = 0; ks < 8; ++ks) {
                const f16x8 aH  = *(const f16x8*)&XH[1][ks * 576 + lbase];
                const f16x8 bl0 = WfL[(nt0 * 8 + ks) * 64 + l];        // L2-resident
                const f16x8 bl1 = WfL[((nt0 + 1) * 8 + ks) * 64 + l];
                acc0 = __builtin_amdgcn_mfma_f32_16x16x32_f16(aH, BH0[ks], acc0, 0, 0, 0);
                acc1 = __builtin_amdgcn_mfma_f32_16x16x32_f16(aH, BH1[ks], acc1, 0, 0, 0);
                acc0 = __builtin_amdgcn_mfma_f32_16x16x32_f16(aH, bl0,     acc0, 0, 0, 0);
                acc1 = __builtin_amdgcn_mfma_f32_16x16x32_f16(aH, bl1,     acc1, 0, 0, 0);
            }
            #pragma unroll
            for (int g = 0; g < 4; ++g) {
                float kv0 = tanhd(acc0[g] + bn0) - xr0[g];
                float kv1 = tanhd(acc1[g] + bn1) - xr1[g];
                pm = fmaxf(pm, fmaxf(fabsf(kv0), fabsf(kv1)));
                k1h[g] = __floats2half2_rn(kv0, kv1);
            }

            // ---- stage 2 ----
            {
                const __half2 h21 = __float2half2_rn(a21);
                #pragma unroll
                for (int g = 0; g < 4; ++g) xt2[g] = __hfma2(h21, k1h[g], x2[g]);
            }
            writeFrag(0, xt2);
            __syncthreads();
            acc0 = {0.f, 0.f, 0.f, 0.f}; acc1 = {0.f, 0.f, 0.f, 0.f};
            matmul(0, acc0, acc1);
            #pragma unroll
            for (int g = 0; g < 4; ++g)
                k2h[g] = __floats2half2_rn(tanhd(acc0[g] + bn0) - __low2float(xt2[g]),
                                           tanhd(acc1[g] + bn1) - __high2float(xt2[g]));

            // ---- stage 3 ----
            {
                const __half2 h31 = __float2half2_rn(a31), h32 = __float2half2_rn(a32);
                #pragma unroll
                for (int g = 0; g < 4; ++g) {
                    __half2 v = __hfma2(h31, k1h[g], x2[g]);
                    xt2[g] = __hfma2(h32, k2h[g], v);
                }
            }
            writeFrag(1, xt2);
            __syncthreads();
            acc0 = {0.f, 0.f, 0.f, 0.f}; acc1 = {0.f, 0.f, 0.f, 0.f};
            matmul(1, acc0, acc1);
            #pragma unroll
            for (int g = 0; g < 4; ++g)
                k3h[g] = __floats2half2_rn(tanhd(acc0[g] + bn0) - __low2float(xt2[g]),
                                           tanhd(acc1[g] + bn1) - __high2float(xt2[g]));

            // ---- stage 4 ----
            {
                const __half2 h41 = __float2half2_rn(a41), h42 = __float2half2_rn(a42),
                              h43 = __float2half2_rn(a43);
                #pragma unroll
                for (int g = 0; g < 4; ++g) {
                    __half2 v = __hfma2(h41, k1h[g], x2[g]);
                    v = __hfma2(h42, k2h[g], v);
                    xt2[g] = __hfma2(h43, k3h[g], v);
                }
            }
            writeFrag(0, xt2);
            __syncthreads();
            acc0 = {0.f, 0.f, 0.f, 0.f}; acc1 = {0.f, 0.f, 0.f, 0.f};
            matmul(0, acc0, acc1);
            #pragma unroll
            for (int g = 0; g < 4; ++g)
                k4h[g] = __floats2half2_rn(tanhd(acc0[g] + bn0) - __low2float(xt2[g]),
                                           tanhd(acc1[g] + bn1) - __high2float(xt2[g]));

            // ---- stage 5 ----
            {
                const __half2 h51 = __float2half2_rn(a51), h52 = __float2half2_rn(a52),
                              h53 = __float2half2_rn(a53), h54 = __float2half2_rn(a54);
                #pragma unroll
                for (int g = 0; g < 4; ++g) {
                    __half2 v = __hfma2(h51, k1h[g], x2[g]);
                    v = __hfma2(h52, k2h[g], v);
                    v = __hfma2(h53, k3h[g], v);
                    xt2[g] = __hfma2(h54, k4h[g], v);
                }
            }
            writeFrag(1, xt2);
            __syncthreads();
            acc0 = {0.f, 0.f, 0.f, 0.f}; acc1 = {0.f, 0.f, 0.f, 0.f};
            matmul(1, acc0, acc1);
            #pragma unroll
            for (int g = 0; g < 4; ++g)
                k5h[g] = __floats2half2_rn(tanhd(acc0[g] + bn0) - __low2float(xt2[g]),
                                           tanhd(acc1[g] + bn1) - __high2float(xt2[g]));

            // ---- stage 6 + fused err/x5 epilogue (f32) ----
            {
                const __half2 h61 = __float2half2_rn(a61), h62 = __float2half2_rn(a62),
                              h63 = __float2half2_rn(a63), h64 = __float2half2_rn(a64),
                              h65 = __float2half2_rn(a65);
                #pragma unroll
                for (int g = 0; g < 4; ++g) {
                    __half2 v = __hfma2(h61, k1h[g], x2[g]);
                    v = __hfma2(h62, k2h[g], v);
                    v = __hfma2(h63, k3h[g], v);
                    v = __hfma2(h64, k4h[g], v);
                    xt2[g] = __hfma2(h65, k5h[g], v);
                }
            }
            writeFrag(0, xt2);
            __syncthreads();
            acc0 = {0.f, 0.f, 0.f, 0.f}; acc1 = {0.f, 0.f, 0.f, 0.f};
            matmul(0, acc0, acc1);
            #pragma unroll
            for (int g = 0; g < 4; ++g) {
                float k60 = tanhd(acc0[g] + bn0) - __low2float(xt2[g]);
                float k61 = tanhd(acc1[g] + bn1) - __high2float(xt2[g]);
                float k10 = __low2float(k1h[g]), k11 = __high2float(k1h[g]);
                float k30 = __low2float(k3h[g]), k31 = __high2float(k3h[g]);
                float k40 = __low2float(k4h[g]), k41 = __high2float(k4h[g]);
                float k50 = __low2float(k5h[g]), k51 = __high2float(k5h[g]);
                float x4e0 = xr0[g] + c41 * k10 + c43 * k30 + c44 * k40 + c45 * k50;
                float x5e0 = xr0[g] + c51 * k10 + c53 * k30 + c54 * k40 + c55 * k50 + c56 * k60;
                float x4e1 = xr1[g] + c41 * k11 + c43 * k31 + c44 * k41 + c45 * k51;
                float x5e1 = xr1[g] + c51 * k11 + c53 * k31 + c54 * k41 + c55 * k51 + c56 * k61;
                xn[rowbase + (size_t)g * UNITS + n0] = x5e0;
                xn[rowbase + (size_t)g * UNITS + n1] = x5e1;
                em = fmaxf(em, fmaxf(fabsf(x5e0 - x4e0), fabsf(x5e1 - x4e1)));
            }
            // next chunk's stage-1 writes buffer 1; stage-6 readers are on
            // buffer 0 past their barrier -> no extra barrier needed.
        }

        blockAtomicMax2(&scal[it % 3], em, redbuf, tid);
        blockAtomicMax2(&scal[3 + it % 3], pm, redbuf, tid);

        grid.sync();

        if (tid == 0) {
            bc2[0] = __uint_as_float(atomicMax(&scal[it % 3], 0u));       // global err
            bc2[1] = __uint_as_float(atomicMax(&scal[3 + it % 3], 0u));   // global pvf
        }
        __syncthreads();
        const float err = bc2[0];
        const float pvfmax = bc2[1];

        // reference checks cond BEFORE the body we just (speculatively) ran
        if (!((t <= 1000.0f) && (pvfmax >= 0.01f))) break;

        const bool accept = (err < 1.0e-3f) || (dt <= 0.01f);
        float dtn = 0.9f * dt * powf(1.0e-3f / (err + 1e-12f), 0.2f);
        dtn = fminf(fmaxf(dtn, 0.01f), 1.0f);

        if (accept) {
            t = t + dt;
            float* tmp = xc; xc = xn; xn = tmp;
        }
        dt = dtn;
    }

    // final x must end in d_out
    if (xc != xA) {
        const f32x4* src = (const f32x4*)xc;
        f32x4* dst = (f32x4*)xA;
        const int total = BATCH * UNITS / 4;
        for (int i = blockIdx.x * TPB + tid; i < total; i += gridDim.x * TPB)
            dst[i] = src[i];
    }
}

// ---- host ----------------------------------------------------------------
extern "C" void kernel_launch(void* const* d_in, const int* in_sizes, int n_in,
                              void* d_out, int out_size, void* d_ws, size_t ws_size,
                              hipStream_t stream)
{
    const float* x0 = (const float*)d_in[0];
    const float* W  = (const float*)d_in[1];
    const float* b  = (const float*)d_in[2];
    float* xA = (float*)d_out;

    const size_t xbytes = (size_t)BATCH * UNITS * sizeof(float);          // 32 MiB
    const size_t wfrag  = (size_t)UNITS * UNITS * sizeof(unsigned short); // 128 KiB

    char* ws = (char*)d_ws;
    unsigned* scal = (unsigned*)ws;                      // 32 B used
    unsigned short* WfH = (unsigned short*)(ws + 4096);
    unsigned short* WfL = (unsigned short*)(ws + 4096 + wfrag);
    float* xB = (float*)(ws + 4096 + 2 * wfrag);

    const size_t req = 4096 + 2 * wfrag + xbytes;        // ~32.3 MB
    if (ws_size < req) return;

    init_ws_kernel<<<(UNITS * UNITS) / 256, 256, 0, stream>>>(W, WfH, WfL, scal);
    (void)hipMemcpyAsync(xA, x0, xbytes, hipMemcpyDeviceToDevice, stream);

    int nb = 0;
    if (hipOccupancyMaxActiveBlocksPerMultiprocessor(&nb, hopfield_solver, TPB, 0) != hipSuccess || nb < 1)
        nb = 1;
    int ncu = 0;
    if (hipDeviceGetAttribute(&ncu, hipDeviceAttributeMultiprocessorCount, 0) != hipSuccess || ncu < 1)
        ncu = 256;
    int gridsz = nb * ncu;
    if (gridsz > NCHUNK) gridsz = NCHUNK;
    if (gridsz < 1) gridsz = 1;

    void* args[6];
    args[0] = (void*)&xA; args[1] = (void*)&xB; args[2] = (void*)&b;
    args[3] = (void*)&WfH; args[4] = (void*)&WfL; args[5] = (void*)&scal;
    (void)hipLaunchCooperativeKernel(hopfield_solver, dim3(gridsz), dim3(TPB), args, 0u, stream);
}

// Round 8
// 6419.366 us; speedup vs baseline: 2.7414x; 2.7414x over previous
//
#include <hip/hip_runtime.h>
#include <hip/hip_cooperative_groups.h>
#include <hip/hip_fp16.h>
#include <math.h>

namespace cg = cooperative_groups;

#define UNITS  256
#define BATCH  32768
#define R      16                 /* rows per chunk */
#define NCHUNK (BATCH / R)        /* 2048 */
#define TPB    512                /* 8 waves, each owns 2 n-tiles (NT=2) */

typedef float    f32x4 __attribute__((ext_vector_type(4)));
typedef _Float16 f16x8 __attribute__((ext_vector_type(8)));

__device__ __forceinline__ float uni(float x) {   // force wave-uniform -> SGPR
    return __uint_as_float(__builtin_amdgcn_readfirstlane(__float_as_uint(x)));
}

__device__ __forceinline__ float tanhd(float v) {
    float e = __expf(v + v);
    return 1.0f - 2.0f / (e + 1.0f);
}

// padded frag layout: unit (16B) -> u16 offset; 16B pad after every 8 units
__device__ __forceinline__ int puidx(int unit) {
    return (unit << 3) + ((unit >> 3) << 3);
}

__device__ __forceinline__ void blockAtomicMax2(unsigned* addr, float v, float* redbuf, int tid)
{
    #pragma unroll
    for (int o = 32; o > 0; o >>= 1) v = fmaxf(v, __shfl_xor(v, o, 64));
    if ((tid & 63) == 0) redbuf[tid >> 6] = v;
    __syncthreads();
    if (tid == 0) {
        float m = redbuf[0];
        #pragma unroll
        for (int i = 1; i < TPB / 64; ++i) m = fmaxf(m, redbuf[i]);
        atomicMax(addr, __float_as_uint(m));   // values >= 0: uint order == float order
    }
    __syncthreads();
}

// ---- init: symmetric zero-diag Ws -> fp16 hi + fp16 lo, B-fragment order ----
__global__ void init_ws_kernel(const float* __restrict__ W,
                               unsigned short* __restrict__ WfH,
                               unsigned short* __restrict__ WfL,
                               unsigned* __restrict__ scal)
{
    const int i = blockIdx.x * 256 + threadIdx.x;    // 0..65535
    const int k = i >> 8, n = i & 255;
    float v = 0.5f * (W[(k << 8) + n] + W[(n << 8) + k]);
    if (k == n) v = 0.0f;
    __half h = __float2half_rn(v);
    __half l = __float2half_rn(v - __half2float(h));
    // fragment order: [nt(16)][ks(8)][lane(64)][slot(8)]
    const int nt = n >> 4, ks = k >> 5;
    const int lane = (n & 15) + (((k >> 3) & 3) << 4);
    const int slot = k & 7;
    const int off = ((nt * 8 + ks) * 64 + lane) * 8 + slot;
    WfH[off] = __half_as_ushort(h);
    WfL[off] = __half_as_ushort(l);
    if (i < 8) scal[i] = 0u;
}

// ---- persistent cooperative solver --------------------------------------
__global__ void __launch_bounds__(TPB, 2) hopfield_solver(
    float* __restrict__ xA, float* __restrict__ xB,
    const float* __restrict__ bvec,
    const f16x8* __restrict__ WfH, const f16x8* __restrict__ WfL,
    unsigned* __restrict__ scal)
{
    cg::grid_group grid = cg::this_grid();
    __shared__ __align__(16) unsigned short XH[2][4608];   // fp16 A-frags, dbuf
    __shared__ float redbuf[TPB / 64];
    __shared__ float bc2[2];

    const int tid = threadIdx.x;
    const int l = tid & 63, w = tid >> 6;        // 8 waves

    // ownership: wave w -> n-tiles 2w, 2w+1; thread: cols n0, n1; rows mb..mb+3
    const int n0 = (w << 5) + (l & 15);
    const int n1 = n0 + 16;
    const int mb = (l >> 4) << 2;
    const float bn0 = bvec[n0], bn1 = bvec[n1];
    const int nt0 = w * 2;

    // A-frag write targets (mapping verified in R4-R7)
    const int s_slot = l & 7;
    const int gk0 = (l & 15) >> 3;
    const int pb0 = puidx((n0 >> 5) * 64 + gk0 * 16 + mb) + s_slot;       // + 8*g
    const int pb1 = puidx((n0 >> 5) * 64 + (gk0 + 2) * 16 + mb) + s_slot; // + 8*g
    // A-frag read base: unit ks*64 + l  ->  u16 offset ks*576 + lbase
    const int lbase = (l << 3) + ((l >> 3) << 3);

    // resident W-hi fp16 B-fragments for this wave's two n-tiles (64 VGPR)
    f16x8 BH0[8], BH1[8];
    #pragma unroll
    for (int ks = 0; ks < 8; ++ks) {
        BH0[ks] = WfH[(nt0 * 8 + ks) * 64 + l];
        BH1[ks] = WfH[((nt0 + 1) * 8 + ks) * 64 + l];
    }

    // f32 -> fp16 (single rounding) A-frag store
    auto writeFragF = [&](int p, const float (&v0)[4], const float (&v1)[4]) {
        #pragma unroll
        for (int g = 0; g < 4; ++g) {
            XH[p][pb0 + 8 * g] = __half_as_ushort(__float2half_rn(v0[g]));
            XH[p][pb1 + 8 * g] = __half_as_ushort(__float2half_rn(v1[g]));
        }
    };

    auto matmul = [&](int p, f32x4& acc0, f32x4& acc1) {   // 1-term fp16 (W-hi)
        #pragma unroll
        for (int ks = 0; ks < 8; ++ks) {
            const f16x8 aH = *(const f16x8*)&XH[p][ks * 576 + lbase];
            acc0 = __builtin_amdgcn_mfma_f32_16x16x32_f16(aH, BH0[ks], acc0, 0, 0, 0);
            acc1 = __builtin_amdgcn_mfma_f32_16x16x32_f16(aH, BH1[ks], acc1, 0, 0, 0);
        }
    };

    float* xc = xA;   // current x (d_out holds x0)
    float* xn = xB;
    float t = 0.0f, dt = 0.1f;

    for (int it = 0; it < 100000; ++it) {
        if (blockIdx.x == 0 && tid == 0) {
            scal[(it + 1) % 3] = 0u;          // err slot for next iter
            scal[3 + (it + 1) % 3] = 0u;      // pvf slot for next iter
        }

        // dt-premultiplied RKF coefficients, forced uniform (SGPR)
        const float a21 = uni(0.25f * dt);
        const float a31 = uni((float)(3.0 / 32.0) * dt),   a32 = uni((float)(9.0 / 32.0) * dt);
        const float a41 = uni((float)(1932.0 / 2197.0) * dt), a42 = uni((float)(-7200.0 / 2197.0) * dt),
                    a43 = uni((float)(7296.0 / 2197.0) * dt);
        const float a51 = uni((float)(439.0 / 216.0) * dt), a52 = uni(-8.0f * dt),
                    a53 = uni((float)(3680.0 / 513.0) * dt), a54 = uni((float)(-845.0 / 4104.0) * dt);
        const float a61 = uni((float)(-8.0 / 27.0) * dt),  a62 = uni(2.0f * dt),
                    a63 = uni((float)(-3544.0 / 2565.0) * dt), a64 = uni((float)(1859.0 / 4104.0) * dt),
                    a65 = uni((float)(-11.0 / 40.0) * dt);
        const float c41 = uni((float)(25.0 / 216.0) * dt), c43 = uni((float)(1408.0 / 2565.0) * dt),
                    c44 = uni((float)(2197.0 / 4104.0) * dt), c45 = uni(-0.2f * dt);
        const float c51 = uni((float)(16.0 / 135.0) * dt), c53 = uni((float)(6656.0 / 12825.0) * dt),
                    c54 = uni((float)(28561.0 / 56430.0) * dt), c55 = uni((float)(-9.0 / 50.0) * dt),
                    c56 = uni((float)(2.0 / 55.0) * dt);

        float em = 0.0f, pm = 0.0f;

        for (int ch = blockIdx.x; ch < NCHUNK; ch += gridDim.x) {
            const size_t rowbase = (size_t)(ch * R + mb) * UNITS;

            float xr0[4], xr1[4], xt0[4], xt1[4];
            float k1a[4], k1b[4], k2a[4], k2b[4], k3a[4], k3b[4];
            float k4a[4], k4b[4], k5a[4], k5b[4];
            f32x4 acc0, acc1;

            #pragma unroll
            for (int g = 0; g < 4; ++g) {
                xr0[g] = xc[rowbase + (size_t)g * UNITS + n0];
                xr1[g] = xc[rowbase + (size_t)g * UNITS + n1];
            }

            // prefetch W-lo fragments (L2-hot) so latency hides under barrier
            f16x8 blA[8], blB[8];
            #pragma unroll
            for (int ks = 0; ks < 8; ++ks) {
                blA[ks] = WfL[(nt0 * 8 + ks) * 64 + l];
                blB[ks] = WfL[((nt0 + 1) * 8 + ks) * 64 + l];
            }

            // ---- stage 1: k1 = pvf(x); A = fp16(x), B = Wh + Wl (2-term) ----
            writeFragF(1, xr0, xr1);
            __syncthreads();
            acc0 = {0.f, 0.f, 0.f, 0.f}; acc1 = {0.f, 0.f, 0.f, 0.f};
            #pragma unroll
            for (int ks = 0; ks < 8; ++ks) {
                const f16x8 aH = *(const f16x8*)&XH[1][ks * 576 + lbase];
                acc0 = __builtin_amdgcn_mfma_f32_16x16x32_f16(aH, BH0[ks], acc0, 0, 0, 0);
                acc1 = __builtin_amdgcn_mfma_f32_16x16x32_f16(aH, BH1[ks], acc1, 0, 0, 0);
                acc0 = __builtin_amdgcn_mfma_f32_16x16x32_f16(aH, blA[ks], acc0, 0, 0, 0);
                acc1 = __builtin_amdgcn_mfma_f32_16x16x32_f16(aH, blB[ks], acc1, 0, 0, 0);
            }
            #pragma unroll
            for (int g = 0; g < 4; ++g) {
                float kv0 = tanhd(acc0[g] + bn0) - xr0[g];
                float kv1 = tanhd(acc1[g] + bn1) - xr1[g];
                k1a[g] = kv0; k1b[g] = kv1;
                pm = fmaxf(pm, fmaxf(fabsf(kv0), fabsf(kv1)));
            }

            // ---- stage 2 ----
            #pragma unroll
            for (int g = 0; g < 4; ++g) {
                xt0[g] = fmaf(a21, k1a[g], xr0[g]);
                xt1[g] = fmaf(a21, k1b[g], xr1[g]);
            }
            writeFragF(0, xt0, xt1);
            __syncthreads();
            acc0 = {0.f, 0.f, 0.f, 0.f}; acc1 = {0.f, 0.f, 0.f, 0.f};
            matmul(0, acc0, acc1);
            #pragma unroll
            for (int g = 0; g < 4; ++g) {
                k2a[g] = tanhd(acc0[g] + bn0) - xt0[g];
                k2b[g] = tanhd(acc1[g] + bn1) - xt1[g];
            }

            // ---- stage 3 ----
            #pragma unroll
            for (int g = 0; g < 4; ++g) {
                float v0 = fmaf(a31, k1a[g], xr0[g]); v0 = fmaf(a32, k2a[g], v0);
                float v1 = fmaf(a31, k1b[g], xr1[g]); v1 = fmaf(a32, k2b[g], v1);
                xt0[g] = v0; xt1[g] = v1;
            }
            writeFragF(1, xt0, xt1);
            __syncthreads();
            acc0 = {0.f, 0.f, 0.f, 0.f}; acc1 = {0.f, 0.f, 0.f, 0.f};
            matmul(1, acc0, acc1);
            #pragma unroll
            for (int g = 0; g < 4; ++g) {
                k3a[g] = tanhd(acc0[g] + bn0) - xt0[g];
                k3b[g] = tanhd(acc1[g] + bn1) - xt1[g];
            }

            // ---- stage 4 ----
            #pragma unroll
            for (int g = 0; g < 4; ++g) {
                float v0 = fmaf(a41, k1a[g], xr0[g]); v0 = fmaf(a42, k2a[g], v0); v0 = fmaf(a43, k3a[g], v0);
                float v1 = fmaf(a41, k1b[g], xr1[g]); v1 = fmaf(a42, k2b[g], v1); v1 = fmaf(a43, k3b[g], v1);
                xt0[g] = v0; xt1[g] = v1;
            }
            writeFragF(0, xt0, xt1);
            __syncthreads();
            acc0 = {0.f, 0.f, 0.f, 0.f}; acc1 = {0.f, 0.f, 0.f, 0.f};
            matmul(0, acc0, acc1);
            #pragma unroll
            for (int g = 0; g < 4; ++g) {
                k4a[g] = tanhd(acc0[g] + bn0) - xt0[g];
                k4b[g] = tanhd(acc1[g] + bn1) - xt1[g];
            }

            // ---- stage 5 ----
            #pragma unroll
            for (int g = 0; g < 4; ++g) {
                float v0 = fmaf(a51, k1a[g], xr0[g]); v0 = fmaf(a52, k2a[g], v0);
                v0 = fmaf(a53, k3a[g], v0); v0 = fmaf(a54, k4a[g], v0);
                float v1 = fmaf(a51, k1b[g], xr1[g]); v1 = fmaf(a52, k2b[g], v1);
                v1 = fmaf(a53, k3b[g], v1); v1 = fmaf(a54, k4b[g], v1);
                xt0[g] = v0; xt1[g] = v1;
            }
            writeFragF(1, xt0, xt1);
            __syncthreads();
            acc0 = {0.f, 0.f, 0.f, 0.f}; acc1 = {0.f, 0.f, 0.f, 0.f};
            matmul(1, acc0, acc1);
            #pragma unroll
            for (int g = 0; g < 4; ++g) {
                k5a[g] = tanhd(acc0[g] + bn0) - xt0[g];
                k5b[g] = tanhd(acc1[g] + bn1) - xt1[g];
            }

            // ---- stage 6 + fused err/x5 epilogue ----
            #pragma unroll
            for (int g = 0; g < 4; ++g) {
                float v0 = fmaf(a61, k1a[g], xr0[g]); v0 = fmaf(a62, k2a[g], v0);
                v0 = fmaf(a63, k3a[g], v0); v0 = fmaf(a64, k4a[g], v0); v0 = fmaf(a65, k5a[g], v0);
                float v1 = fmaf(a61, k1b[g], xr1[g]); v1 = fmaf(a62, k2b[g], v1);
                v1 = fmaf(a63, k3b[g], v1); v1 = fmaf(a64, k4b[g], v1); v1 = fmaf(a65, k5b[g], v1);
                xt0[g] = v0; xt1[g] = v1;
            }
            writeFragF(0, xt0, xt1);
            __syncthreads();
            acc0 = {0.f, 0.f, 0.f, 0.f}; acc1 = {0.f, 0.f, 0.f, 0.f};
            matmul(0, acc0, acc1);
            #pragma unroll
            for (int g = 0; g < 4; ++g) {
                float k60 = tanhd(acc0[g] + bn0) - xt0[g];
                float k61 = tanhd(acc1[g] + bn1) - xt1[g];
                float x4e0 = xr0[g] + c41 * k1a[g] + c43 * k3a[g] + c44 * k4a[g] + c45 * k5a[g];
                float x5e0 = xr0[g] + c51 * k1a[g] + c53 * k3a[g] + c54 * k4a[g] + c55 * k5a[g] + c56 * k60;
                float x4e1 = xr1[g] + c41 * k1b[g] + c43 * k3b[g] + c44 * k4b[g] + c45 * k5b[g];
                float x5e1 = xr1[g] + c51 * k1b[g] + c53 * k3b[g] + c54 * k4b[g] + c55 * k5b[g] + c56 * k61;
                xn[rowbase + (size_t)g * UNITS + n0] = x5e0;
                xn[rowbase + (size_t)g * UNITS + n1] = x5e1;
                em = fmaxf(em, fmaxf(fabsf(x5e0 - x4e0), fabsf(x5e1 - x4e1)));
            }
            // next chunk's stage-1 writes buffer 1; stage-6 readers on buffer 0
            // finish before the stage-1 barrier -> safe without extra barrier.
        }

        blockAtomicMax2(&scal[it % 3], em, redbuf, tid);
        blockAtomicMax2(&scal[3 + it % 3], pm, redbuf, tid);

        grid.sync();

        if (tid == 0) {
            bc2[0] = __uint_as_float(atomicMax(&scal[it % 3], 0u));       // global err
            bc2[1] = __uint_as_float(atomicMax(&scal[3 + it % 3], 0u));   // global pvf
        }
        __syncthreads();
        const float err = bc2[0];
        const float pvfmax = bc2[1];

        // reference checks cond BEFORE the body we just (speculatively) ran
        if (!((t <= 1000.0f) && (pvfmax >= 0.01f))) break;

        const bool accept = (err < 1.0e-3f) || (dt <= 0.01f);
        float dtn = 0.9f * dt * powf(1.0e-3f / (err + 1e-12f), 0.2f);
        dtn = fminf(fmaxf(dtn, 0.01f), 1.0f);

        if (accept) {
            t = t + dt;
            float* tmp = xc; xc = xn; xn = tmp;
        }
        dt = dtn;
    }

    // final x must end in d_out
    if (xc != xA) {
        const f32x4* src = (const f32x4*)xc;
        f32x4* dst = (f32x4*)xA;
        const int total = BATCH * UNITS / 4;
        for (int i = blockIdx.x * TPB + tid; i < total; i += gridDim.x * TPB)
            dst[i] = src[i];
    }
}

// ---- host ----------------------------------------------------------------
extern "C" void kernel_launch(void* const* d_in, const int* in_sizes, int n_in,
                              void* d_out, int out_size, void* d_ws, size_t ws_size,
                              hipStream_t stream)
{
    const float* x0 = (const float*)d_in[0];
    const float* W  = (const float*)d_in[1];
    const float* b  = (const float*)d_in[2];
    float* xA = (float*)d_out;

    const size_t xbytes = (size_t)BATCH * UNITS * sizeof(float);          // 32 MiB
    const size_t wfrag  = (size_t)UNITS * UNITS * sizeof(unsigned short); // 128 KiB

    char* ws = (char*)d_ws;
    unsigned* scal = (unsigned*)ws;                      // 32 B used
    unsigned short* WfH = (unsigned short*)(ws + 4096);
    unsigned short* WfL = (unsigned short*)(ws + 4096 + wfrag);
    float* xB = (float*)(ws + 4096 + 2 * wfrag);

    const size_t req = 4096 + 2 * wfrag + xbytes;        // ~32.3 MB
    if (ws_size < req) return;

    init_ws_kernel<<<(UNITS * UNITS) / 256, 256, 0, stream>>>(W, WfH, WfL, scal);
    (void)hipMemcpyAsync(xA, x0, xbytes, hipMemcpyDeviceToDevice, stream);

    int nb = 0;
    if (hipOccupancyMaxActiveBlocksPerMultiprocessor(&nb, hopfield_solver, TPB, 0) != hipSuccess || nb < 1)
        nb = 1;
    int ncu = 0;
    if (hipDeviceGetAttribute(&ncu, hipDeviceAttributeMultiprocessorCount, 0) != hipSuccess || ncu < 1)
        ncu = 256;
    int gridsz = nb * ncu;
    if (gridsz > NCHUNK) gridsz = NCHUNK;
    if (gridsz < 1) gridsz = 1;

    void* args[6];
    args[0] = (void*)&xA; args[1] = (void*)&xB; args[2] = (void*)&b;
    args[3] = (void*)&WfH; args[4] = (void*)&WfL; args[5] = (void*)&scal;
    (void)hipLaunchCooperativeKernel(hopfield_solver, dim3(gridsz), dim3(TPB), args, 0u, stream);
}